// Round 1
// baseline (358.929 us; speedup 1.0000x reference)
//
#include <hip/hip_runtime.h>
#include <math.h>

// Problem shapes (fixed by reference setup_inputs)
#define B    256
#define S    196
#define D    1024
#define P    512
#define L    8
#define TOPK 4

#define SSPLIT 7                 // S = 7 * 28
#define SCHUNK (S / SSPLIT)      // 28
#define OUTSTRIDE (TOPK * L * D) // 32768 floats per b in out

// ---------------------------------------------------------------------------
// Kernel 1: partial sums over S. grid(B, SSPLIT), block(256).
// Writes partials into the FIRST 7168 floats of out[b]'s own 32768-float
// region (scratch-in-out; consumed by kernel 2 before being overwritten).
// 1792 blocks -> 7 blocks/CU, 28 waves/CU; HBM-BW-bound (205 MB read).
// ---------------------------------------------------------------------------
__global__ __launch_bounds__(256) void mean_partial_kernel(
    const float* __restrict__ x, float* __restrict__ scratch) {
  const int b = blockIdx.x;
  const int j = blockIdx.y;
  const int t = threadIdx.x;  // 0..255
  const float* xb = x + (size_t)b * S * D + (size_t)j * SCHUNK * D + t * 4;

  float4 acc = make_float4(0.f, 0.f, 0.f, 0.f);
#pragma unroll 4
  for (int s = 0; s < SCHUNK; ++s) {
    float4 v = *(const float4*)(xb + (size_t)s * D);
    acc.x += v.x; acc.y += v.y; acc.z += v.z; acc.w += v.w;
  }
  *(float4*)(scratch + (size_t)b * OUTSTRIDE + j * D + t * 4) = acc;
}

// ---------------------------------------------------------------------------
// Kernel 2 (fully fused): per batch row b --
//   A: finalize mean from partials (read from out-scratch), |m|^2 -> rq
//   B: GEMV sim[p] = (m . pk[p]) * rsqrt(|pk[p]|^2) * rq  (pk is 2 MiB,
//      L2-resident per XCD; wave-per-2-rows, shfl reduce)
//   C: 4 rounds of Gumbel argmax with -1000 mask-out (thread t <-> pool p=t)
//   D: gather 4 selected prompt rows -> out[b] (overwrites the scratch)
// grid(B), block(512). No d_ws, no kn/qn/simp intermediates.
// ---------------------------------------------------------------------------
__global__ __launch_bounds__(512) void fused_select_kernel(
    const float* __restrict__ pk, const float* __restrict__ gu,
    const float* __restrict__ prompt, float* __restrict__ out) {
  const int b = blockIdx.x;
  const int t = threadIdx.x;   // 0..511
  const int lane = t & 63;
  const int wv = t >> 6;       // 0..7

  __shared__ float q[D];       // mean query, 4 KB
  __shared__ float cur[P];     // running sim scores, 2 KB
  __shared__ float wred[8];
  __shared__ int   wids[8];
  __shared__ float s_rq;
  __shared__ int   sidx[TOPK];

  // ---- Phase A: finalize mean + query norm ----
  if (t < 256) {
    const float* part = out + (size_t)b * OUTSTRIDE;  // scratch from K1
    float4 m4 = make_float4(0.f, 0.f, 0.f, 0.f);
#pragma unroll
    for (int j = 0; j < SSPLIT; ++j) {
      float4 v = *(const float4*)(part + j * D + t * 4);
      m4.x += v.x; m4.y += v.y; m4.z += v.z; m4.w += v.w;
    }
    const float inv = 1.0f / (float)S;
    m4.x *= inv; m4.y *= inv; m4.z *= inv; m4.w *= inv;
    *(float4*)(q + t * 4) = m4;
    float ss = m4.x * m4.x + m4.y * m4.y + m4.z * m4.z + m4.w * m4.w;
    for (int off = 32; off > 0; off >>= 1) ss += __shfl_down(ss, off, 64);
    if (lane == 0) wred[wv] = ss;
  }
  __syncthreads();
  if (t == 0) {
    float tot = wred[0] + wred[1] + wred[2] + wred[3];
    s_rq = rsqrtf(fmaxf(tot, 1e-12f));
  }
  __syncthreads();
  const float rq = s_rq;

  // ---- Phase B: sim GEMV with on-the-fly key norms ----
  // wave wv owns rows [wv*64, wv*64+64); 2 rows per pass for MLP.
  {
    const int pbase = wv * 64;
    for (int r = 0; r < 64; r += 2) {
      const float* k0 = pk + (size_t)(pbase + r) * D;
      const float* k1 = pk + (size_t)(pbase + r + 1) * D;
      float s1a = 0.f, s2a = 0.f, s1b = 0.f, s2b = 0.f;
#pragma unroll
      for (int kk = 0; kk < 4; ++kk) {
        const int di = lane * 4 + kk * 256;
        float4 qv = *(const float4*)(q + di);
        float4 ka = *(const float4*)(k0 + di);
        float4 kb = *(const float4*)(k1 + di);
        s1a += qv.x * ka.x + qv.y * ka.y + qv.z * ka.z + qv.w * ka.w;
        s2a += ka.x * ka.x + ka.y * ka.y + ka.z * ka.z + ka.w * ka.w;
        s1b += qv.x * kb.x + qv.y * kb.y + qv.z * kb.z + qv.w * kb.w;
        s2b += kb.x * kb.x + kb.y * kb.y + kb.z * kb.z + kb.w * kb.w;
      }
      for (int off = 32; off > 0; off >>= 1) {
        s1a += __shfl_down(s1a, off, 64);
        s2a += __shfl_down(s2a, off, 64);
        s1b += __shfl_down(s1b, off, 64);
        s2b += __shfl_down(s2b, off, 64);
      }
      if (lane == 0) {
        cur[pbase + r]     = s1a * rsqrtf(fmaxf(s2a, 1e-12f)) * rq;
        cur[pbase + r + 1] = s1b * rsqrtf(fmaxf(s2b, 1e-12f)) * rq;
      }
    }
  }
  __syncthreads();

  // ---- Phase C: 4 rounds of Gumbel argmax (thread t <-> pool entry t) ----
  for (int i = 0; i < TOPK; ++i) {
    const float u = gu[((size_t)i * B + b) * P + t];
    const float g = -logf(-logf(u + 1e-10f) + 1e-10f);
    float v = cur[t] + g;
    int idx = t;
    for (int off = 32; off > 0; off >>= 1) {
      float ov = __shfl_down(v, off, 64);
      int oi = __shfl_down(idx, off, 64);
      if (ov > v || (ov == v && oi < idx)) { v = ov; idx = oi; }
    }
    if (lane == 0) { wred[wv] = v; wids[wv] = idx; }
    __syncthreads();
    if (t == 0) {
      float bv = wred[0]; int bi = wids[0];
#pragma unroll
      for (int k = 1; k < 8; ++k)
        if (wred[k] > bv || (wred[k] == bv && wids[k] < bi)) {
          bv = wred[k]; bi = wids[k];
        }
      sidx[i] = bi;
      cur[bi] -= 1000.0f;  // hard mask-out for next round
    }
    __syncthreads();
  }

  // ---- Phase D: gather selected prompt rows (overwrites scratch) ----
#pragma unroll
  for (int i = 0; i < TOPK; ++i) {
    const int p = sidx[i];
    const float4* src = (const float4*)(prompt + (size_t)p * L * D);
    float4* dst = (float4*)(out + (size_t)b * OUTSTRIDE + i * (L * D));
#pragma unroll
    for (int c = 0; c < (L * D / 4) / 512; ++c) {  // 2048/512 = 4
      dst[c * 512 + t] = src[c * 512 + t];
    }
  }
}

// ---------------------------------------------------------------------------
extern "C" void kernel_launch(void* const* d_in, const int* in_sizes, int n_in,
                              void* d_out, int out_size, void* d_ws,
                              size_t ws_size, hipStream_t stream) {
  const float* x_embed    = (const float*)d_in[0];  // [B,S,D]
  const float* prompt     = (const float*)d_in[1];  // [P,L,D]
  const float* prompt_key = (const float*)d_in[2];  // [P,D]
  const float* gumbel_u   = (const float*)d_in[3];  // [TOPK,B,P]
  float* out = (float*)d_out;                       // [B,TOPK*L,D]

  // d_ws deliberately unused: partial sums live in out[b]'s own region
  // (first 7168 of 32768 floats), read by K2 Phase A before Phase D
  // overwrites them. No cross-block hazard; stream-ordered K1 -> K2.
  mean_partial_kernel<<<dim3(B, SSPLIT), 256, 0, stream>>>(x_embed, out);
  fused_select_kernel<<<B, 512, 0, stream>>>(prompt_key, gumbel_u, prompt,
                                             out);
}

// Round 2
// 331.965 us; speedup vs baseline: 1.0812x; 1.0812x over previous
//
#include <hip/hip_runtime.h>
#include <math.h>

// Problem shapes (fixed by reference setup_inputs)
#define B    256
#define S    196
#define D    1024
#define P    512
#define L    8
#define TOPK 4

#define SSPLIT 7          // S = 7 * 28
#define SCHUNK (S / SSPLIT)
#define KSPLIT 8          // split-K for sim

// ---------------------------------------------------------------------------
// Kernel 1: partial sums over S. grid(B, SSPLIT), block(256).
// 1792 blocks -> 7 blocks/CU, 28 waves/CU; float4 streaming, HBM-BW-bound
// (205 MB read at ~6.3 TB/s achievable => ~34 us floor).
// ---------------------------------------------------------------------------
__global__ __launch_bounds__(256) void mean_partial_kernel(
    const float* __restrict__ x, float* __restrict__ part) {
  const int b = blockIdx.x;
  const int j = blockIdx.y;
  const int t = threadIdx.x;  // 0..255
  const float* xb = x + (size_t)b * S * D + (size_t)j * SCHUNK * D + t * 4;

  float4 acc = make_float4(0.f, 0.f, 0.f, 0.f);
#pragma unroll 4
  for (int s = 0; s < SCHUNK; ++s) {
    float4 v = *(const float4*)(xb + (size_t)s * D);
    acc.x += v.x; acc.y += v.y; acc.z += v.z; acc.w += v.w;
  }
  *(float4*)(part + ((size_t)b * SSPLIT + j) * D + t * 4) = acc;
}

// ---------------------------------------------------------------------------
// Kernel 2 (merged): blocks [0,B) finalize mean+L2norm -> qn;
// blocks [B, B+P) L2-normalize prompt_key -> kn. block(256). ~2-3 us.
// ---------------------------------------------------------------------------
__global__ __launch_bounds__(256) void norm_kernel(
    const float* __restrict__ part, const float* __restrict__ pk,
    float* __restrict__ qn, float* __restrict__ kn) {
  const int t = threadIdx.x;
  float4 acc;
  float* dst;

  if (blockIdx.x < B) {
    const int b = blockIdx.x;
    acc = make_float4(0.f, 0.f, 0.f, 0.f);
#pragma unroll
    for (int j = 0; j < SSPLIT; ++j) {
      float4 v = *(const float4*)(part + ((size_t)b * SSPLIT + j) * D + t * 4);
      acc.x += v.x; acc.y += v.y; acc.z += v.z; acc.w += v.w;
    }
    const float inv = 1.0f / (float)S;
    acc.x *= inv; acc.y *= inv; acc.z *= inv; acc.w *= inv;
    dst = qn + (size_t)b * D + t * 4;
  } else {
    const int p = blockIdx.x - B;
    acc = *(const float4*)(pk + (size_t)p * D + t * 4);
    dst = kn + (size_t)p * D + t * 4;
  }

  float ss = acc.x * acc.x + acc.y * acc.y + acc.z * acc.z + acc.w * acc.w;
  for (int off = 32; off > 0; off >>= 1) ss += __shfl_down(ss, off, 64);
  __shared__ float wsum[4];
  __shared__ float snorm;
  const int lane = t & 63, w = t >> 6;
  if (lane == 0) wsum[w] = ss;
  __syncthreads();
  if (t == 0) {
    float tot = wsum[0] + wsum[1] + wsum[2] + wsum[3];
    snorm = rsqrtf(fmaxf(tot, 1e-12f));
  }
  __syncthreads();
  const float r = snorm;
  *(float4*)dst = make_float4(acc.x * r, acc.y * r, acc.z * r, acc.w * r);
}

// ---------------------------------------------------------------------------
// Kernel 3: sim partials = q_n @ key_n^T, split-K=8, NO atomics:
// simp[z][b][p]. grid(B/64, P/64, KSPLIT), block(256), 64x64 tile, 4x4 micro.
// ~16 MB global traffic (L2-resident), 268 MFLOP fp32. ~5-8 us.
// ---------------------------------------------------------------------------
#define KK 16
__global__ __launch_bounds__(256) void sim_kernel(
    const float* __restrict__ qn, const float* __restrict__ kn,
    float* __restrict__ simp) {
  const int b0 = blockIdx.x * 64;
  const int p0 = blockIdx.y * 64;
  const int z  = blockIdx.z;
  const int k0 = z * (D / KSPLIT);  // 128 per split
  const int t = threadIdx.x;
  const int tx = t & 15;   // p micro index
  const int ty = t >> 4;   // b micro index

  __shared__ float As[KK][68];  // [k][b]
  __shared__ float Bs[KK][68];  // [k][p]

  float acc[4][4];
#pragma unroll
  for (int i = 0; i < 4; ++i)
#pragma unroll
    for (int j = 0; j < 4; ++j) acc[i][j] = 0.f;

  const int rr = t >> 2;        // 0..63 : row within tile
  const int k4 = (t & 3) * 4;   // 0,4,8,12

  for (int kt = 0; kt < D / KSPLIT; kt += KK) {
    float4 a = *(const float4*)(qn + (size_t)(b0 + rr) * D + k0 + kt + k4);
    float4 bb = *(const float4*)(kn + (size_t)(p0 + rr) * D + k0 + kt + k4);
    As[k4 + 0][rr] = a.x; As[k4 + 1][rr] = a.y;
    As[k4 + 2][rr] = a.z; As[k4 + 3][rr] = a.w;
    Bs[k4 + 0][rr] = bb.x; Bs[k4 + 1][rr] = bb.y;
    Bs[k4 + 2][rr] = bb.z; Bs[k4 + 3][rr] = bb.w;
    __syncthreads();
#pragma unroll
    for (int kk = 0; kk < KK; ++kk) {
      float4 av = *(const float4*)&As[kk][ty * 4];
      float4 bv = *(const float4*)&Bs[kk][tx * 4];
      acc[0][0] += av.x * bv.x; acc[0][1] += av.x * bv.y;
      acc[0][2] += av.x * bv.z; acc[0][3] += av.x * bv.w;
      acc[1][0] += av.y * bv.x; acc[1][1] += av.y * bv.y;
      acc[1][2] += av.y * bv.z; acc[1][3] += av.y * bv.w;
      acc[2][0] += av.z * bv.x; acc[2][1] += av.z * bv.y;
      acc[2][2] += av.z * bv.z; acc[2][3] += av.z * bv.w;
      acc[3][0] += av.w * bv.x; acc[3][1] += av.w * bv.y;
      acc[3][2] += av.w * bv.z; acc[3][3] += av.w * bv.w;
    }
    __syncthreads();
  }
#pragma unroll
  for (int i = 0; i < 4; ++i)
#pragma unroll
    for (int j = 0; j < 4; ++j)
      simp[((size_t)z * B + b0 + ty * 4 + i) * P + p0 + tx * 4 + j] =
          acc[i][j];
}

// ---------------------------------------------------------------------------
// Kernel 4: select only. grid(B), block(512) -- one thread per pool entry.
// Reduce split-K partials in-register, precompute all 4 Gumbel noises,
// 4 argmax rounds with in-register mask-out, write sidx[b][4]. ~2 us.
// ---------------------------------------------------------------------------
__global__ __launch_bounds__(512) void select_kernel(
    const float* __restrict__ simp, const float* __restrict__ gu,
    int* __restrict__ sidx) {
  const int b = blockIdx.x;
  const int t = threadIdx.x;  // == pool index p
  const int lane = t & 63, wv = t >> 6;

  float c = 0.f;
#pragma unroll
  for (int z = 0; z < KSPLIT; ++z)
    c += simp[((size_t)z * B + b) * P + t];

  float g[TOPK];
#pragma unroll
  for (int i = 0; i < TOPK; ++i) {
    float u = gu[((size_t)i * B + b) * P + t];
    g[i] = -logf(-logf(u + 1e-10f) + 1e-10f);
  }

  __shared__ float wval[8];
  __shared__ int   widx[8];
  __shared__ int   ssel[TOPK];

  for (int i = 0; i < TOPK; ++i) {
    float v = c + g[i];
    int idx = t;
    for (int off = 32; off > 0; off >>= 1) {
      float ov = __shfl_down(v, off, 64);
      int oi = __shfl_down(idx, off, 64);
      if (ov > v || (ov == v && oi < idx)) { v = ov; idx = oi; }
    }
    if (lane == 0) { wval[wv] = v; widx[wv] = idx; }
    __syncthreads();
    if (t == 0) {
      float bv = wval[0]; int bi = widx[0];
#pragma unroll
      for (int k = 1; k < 8; ++k)
        if (wval[k] > bv || (wval[k] == bv && widx[k] < bi)) {
          bv = wval[k]; bi = widx[k];
        }
      ssel[i] = bi;
    }
    __syncthreads();
    if (t == ssel[i]) c -= 1000.0f;  // hard mask-out, in-register
  }
  if (t < TOPK) sidx[b * TOPK + t] = ssel[t];
}

// ---------------------------------------------------------------------------
// Kernel 5: gather. grid(B*TOPK, 2), block(256). 2048 blocks -> 8/CU,
// full occupancy for the 32 MB write + 16 MB (L2/L3-resident) read.
// Each block copies half of one selected prompt row (16 KB). ~8-11 us.
// ---------------------------------------------------------------------------
__global__ __launch_bounds__(256) void gather_kernel(
    const int* __restrict__ sidx, const float* __restrict__ prompt,
    float* __restrict__ out) {
  const int bi = blockIdx.x;        // b*TOPK + i
  const int h = blockIdx.y;         // half: 0 or 1
  const int t = threadIdx.x;
  const int p = sidx[bi];
  const float4* src =
      (const float4*)(prompt + (size_t)p * L * D) + h * 1024;
  float4* dst = (float4*)(out + (size_t)bi * (L * D)) + h * 1024;
#pragma unroll
  for (int c = 0; c < 4; ++c)       // 1024 float4 / 256 threads
    dst[c * 256 + t] = src[c * 256 + t];
}

// ---------------------------------------------------------------------------
extern "C" void kernel_launch(void* const* d_in, const int* in_sizes, int n_in,
                              void* d_out, int out_size, void* d_ws,
                              size_t ws_size, hipStream_t stream) {
  const float* x_embed    = (const float*)d_in[0];  // [B,S,D]
  const float* prompt     = (const float*)d_in[1];  // [P,L,D]
  const float* prompt_key = (const float*)d_in[2];  // [P,D]
  const float* gumbel_u   = (const float*)d_in[3];  // [TOPK,B,P]
  float* out = (float*)d_out;                       // [B,TOPK*L,D]

  // ws layout (~14 MB): simp | q_n | key_n | part | sidx
  float* simp = (float*)d_ws;                      // KSPLIT*B*P = 1048576 f
  float* qn   = simp + (size_t)KSPLIT * B * P;     // B*D        =  262144 f
  float* kn   = qn + (size_t)B * D;                // P*D        =  524288 f
  float* part = kn + (size_t)P * D;                // B*SSPLIT*D = 1835008 f
  int*   sidx = (int*)(part + (size_t)B * SSPLIT * D);  // B*TOPK ints

  mean_partial_kernel<<<dim3(B, SSPLIT), 256, 0, stream>>>(x_embed, part);
  norm_kernel<<<B + P, 256, 0, stream>>>(part, prompt_key, qn, kn);
  sim_kernel<<<dim3(B / 64, P / 64, KSPLIT), 256, 0, stream>>>(qn, kn, simp);
  select_kernel<<<B, 512, 0, stream>>>(simp, gumbel_u, sidx);
  gather_kernel<<<dim3(B * TOPK, 2), 256, 0, stream>>>(sidx, prompt, out);
}

// Round 3
// 327.197 us; speedup vs baseline: 1.0970x; 1.0146x over previous
//
#include <hip/hip_runtime.h>
#include <math.h>

// Problem shapes (fixed by reference setup_inputs)
#define B    256
#define S    196
#define D    1024
#define P    512
#define L    8
#define TOPK 4

#define KSPLIT 8          // split-K for sim
#define RPG 49            // rows per group in K1 (S = 4 * 49)
#define PKB 32            // pk-norm blocks appended to K1 grid
#define PK_PER_BLOCK 16   // 16 waves/block -> 16 pk rows

// ---------------------------------------------------------------------------
// Kernel 1 (fused mean + both norms):
//  blocks [0,B): one block per batch row. 1024 threads = 16 waves; thread
//  (g,c) sums rows [g*49, g*49+49) of d-chunk c. LDS tree-reduce the 4
//  groups -> mean vector qm[b][:] + alpha[b] = rsqrt(max(|m|^2,eps)).
//  205 MB HBM read, 2 blocks/CU resident (32 waves/CU) -> BW-bound ~33 us.
//  blocks [B, B+PKB): wave w computes beta[p] = rsqrt(max(|pk_p|^2,eps)).
// Replaces the old part round-trip (7 MB w+r) + separate norm kernel.
// ---------------------------------------------------------------------------
__global__ __launch_bounds__(1024) void query_norm_kernel(
    const float* __restrict__ x, const float* __restrict__ pk,
    float* __restrict__ qm, float* __restrict__ alpha,
    float* __restrict__ beta) {
  const int t = threadIdx.x;
  const int lane = t & 63;
  const int w = t >> 6;  // 0..15

  if (blockIdx.x >= B) {
    // ---- pk norm path: 32 blocks x 16 waves = 512 rows ----
    const int p = (blockIdx.x - B) * PK_PER_BLOCK + w;
    const float* kp = pk + (size_t)p * D;
    float ss = 0.f;
#pragma unroll
    for (int j = 0; j < 4; ++j) {
      float4 v = *(const float4*)(kp + lane * 4 + j * 256);
      ss += v.x * v.x + v.y * v.y + v.z * v.z + v.w * v.w;
    }
    for (int off = 32; off > 0; off >>= 1) ss += __shfl_down(ss, off, 64);
    if (lane == 0) beta[p] = rsqrtf(fmaxf(ss, 1e-12f));
    return;
  }

  // ---- query mean + norm path ----
  const int b = blockIdx.x;
  const int g = t >> 8;   // row group 0..3
  const int c = t & 255;  // d-chunk (4 floats each)
  const float* xb =
      x + (size_t)b * S * D + (size_t)g * RPG * D + c * 4;

  float4 acc = make_float4(0.f, 0.f, 0.f, 0.f);
#pragma unroll 7
  for (int s = 0; s < RPG; ++s) {
    float4 v = *(const float4*)(xb + (size_t)s * D);
    acc.x += v.x; acc.y += v.y; acc.z += v.z; acc.w += v.w;
  }

  __shared__ float4 red[3][256];   // 12 KB
  __shared__ float wsum[4];
  if (g > 0) red[g - 1][c] = acc;
  __syncthreads();

  if (g == 0) {
    float4 r0 = red[0][c], r1 = red[1][c], r2 = red[2][c];
    acc.x += r0.x + r1.x + r2.x;
    acc.y += r0.y + r1.y + r2.y;
    acc.z += r0.z + r1.z + r2.z;
    acc.w += r0.w + r1.w + r2.w;
    const float inv = 1.0f / (float)S;
    acc.x *= inv; acc.y *= inv; acc.z *= inv; acc.w *= inv;
    *(float4*)(qm + (size_t)b * D + c * 4) = acc;
    float ss = acc.x * acc.x + acc.y * acc.y + acc.z * acc.z + acc.w * acc.w;
    for (int off = 32; off > 0; off >>= 1) ss += __shfl_down(ss, off, 64);
    if (lane == 0) wsum[w] = ss;   // w = 0..3 here
  }
  __syncthreads();
  if (t == 0)
    alpha[b] = rsqrtf(fmaxf(wsum[0] + wsum[1] + wsum[2] + wsum[3], 1e-12f));
}

// ---------------------------------------------------------------------------
// Kernel 2: dotraw partials = qm @ pk^T (RAW, unnormalized; alpha/beta are
// applied in select -- scaling is linear so it commutes with split-K sum).
// grid(B/64, P/64, KSPLIT), block(256), 64x64 tile, 4x4 micro. ~4-6 us.
// ---------------------------------------------------------------------------
#define KK 16
__global__ __launch_bounds__(256) void sim_kernel(
    const float* __restrict__ qm, const float* __restrict__ pk,
    float* __restrict__ simp) {
  const int b0 = blockIdx.x * 64;
  const int p0 = blockIdx.y * 64;
  const int z  = blockIdx.z;
  const int k0 = z * (D / KSPLIT);  // 128 per split
  const int t = threadIdx.x;
  const int tx = t & 15;   // p micro index
  const int ty = t >> 4;   // b micro index

  __shared__ float As[KK][68];  // [k][b]
  __shared__ float Bs[KK][68];  // [k][p]

  float acc[4][4];
#pragma unroll
  for (int i = 0; i < 4; ++i)
#pragma unroll
    for (int j = 0; j < 4; ++j) acc[i][j] = 0.f;

  const int rr = t >> 2;        // 0..63 : row within tile
  const int k4 = (t & 3) * 4;   // 0,4,8,12

  for (int kt = 0; kt < D / KSPLIT; kt += KK) {
    float4 a = *(const float4*)(qm + (size_t)(b0 + rr) * D + k0 + kt + k4);
    float4 bb = *(const float4*)(pk + (size_t)(p0 + rr) * D + k0 + kt + k4);
    As[k4 + 0][rr] = a.x; As[k4 + 1][rr] = a.y;
    As[k4 + 2][rr] = a.z; As[k4 + 3][rr] = a.w;
    Bs[k4 + 0][rr] = bb.x; Bs[k4 + 1][rr] = bb.y;
    Bs[k4 + 2][rr] = bb.z; Bs[k4 + 3][rr] = bb.w;
    __syncthreads();
#pragma unroll
    for (int kk = 0; kk < KK; ++kk) {
      float4 av = *(const float4*)&As[kk][ty * 4];
      float4 bv = *(const float4*)&Bs[kk][tx * 4];
      acc[0][0] += av.x * bv.x; acc[0][1] += av.x * bv.y;
      acc[0][2] += av.x * bv.z; acc[0][3] += av.x * bv.w;
      acc[1][0] += av.y * bv.x; acc[1][1] += av.y * bv.y;
      acc[1][2] += av.y * bv.z; acc[1][3] += av.y * bv.w;
      acc[2][0] += av.z * bv.x; acc[2][1] += av.z * bv.y;
      acc[2][2] += av.z * bv.z; acc[2][3] += av.z * bv.w;
      acc[3][0] += av.w * bv.x; acc[3][1] += av.w * bv.y;
      acc[3][2] += av.w * bv.z; acc[3][3] += av.w * bv.w;
    }
    __syncthreads();
  }
#pragma unroll
  for (int i = 0; i < 4; ++i)
#pragma unroll
    for (int j = 0; j < 4; ++j)
      simp[((size_t)z * B + b0 + ty * 4 + i) * P + p0 + tx * 4 + j] =
          acc[i][j];
}

// ---------------------------------------------------------------------------
// Kernel 3: select. grid(B), block(512) -- one thread per pool entry.
// Reduce split-K partials, apply alpha*beta scaling, precompute the 4
// Gumbel noises, 4 argmax rounds with in-register mask-out. ~3 us.
// ---------------------------------------------------------------------------
__global__ __launch_bounds__(512) void select_kernel(
    const float* __restrict__ simp, const float* __restrict__ alpha,
    const float* __restrict__ beta, const float* __restrict__ gu,
    int* __restrict__ sidx) {
  const int b = blockIdx.x;
  const int t = threadIdx.x;  // == pool index p
  const int lane = t & 63, wv = t >> 6;

  float c = 0.f;
#pragma unroll
  for (int z = 0; z < KSPLIT; ++z)
    c += simp[((size_t)z * B + b) * P + t];
  c *= alpha[b] * beta[t];    // sim[b][p] = dotraw * rq * rk

  float g[TOPK];
#pragma unroll
  for (int i = 0; i < TOPK; ++i) {
    float u = gu[((size_t)i * B + b) * P + t];
    g[i] = -logf(-logf(u + 1e-10f) + 1e-10f);
  }

  __shared__ float wval[8];
  __shared__ int   widx[8];
  __shared__ int   ssel[TOPK];

  for (int i = 0; i < TOPK; ++i) {
    float v = c + g[i];
    int idx = t;
    for (int off = 32; off > 0; off >>= 1) {
      float ov = __shfl_down(v, off, 64);
      int oi = __shfl_down(idx, off, 64);
      if (ov > v || (ov == v && oi < idx)) { v = ov; idx = oi; }
    }
    if (lane == 0) { wval[wv] = v; widx[wv] = idx; }
    __syncthreads();
    if (t == 0) {
      float bv = wval[0]; int bi = widx[0];
#pragma unroll
      for (int k = 1; k < 8; ++k)
        if (wval[k] > bv || (wval[k] == bv && widx[k] < bi)) {
          bv = wval[k]; bi = widx[k];
        }
      ssel[i] = bi;
    }
    __syncthreads();
    if (t == ssel[i]) c -= 1000.0f;  // hard mask-out, in-register
  }
  if (t < TOPK) sidx[b * TOPK + t] = ssel[t];
}

// ---------------------------------------------------------------------------
// Kernel 4: gather. grid(B*TOPK, 2), block(256). 2048 blocks -> 8/CU.
// 32 MB write + 16 MB read, bit-exact row copies. ~8 us.
// ---------------------------------------------------------------------------
__global__ __launch_bounds__(256) void gather_kernel(
    const int* __restrict__ sidx, const float* __restrict__ prompt,
    float* __restrict__ out) {
  const int bi = blockIdx.x;        // b*TOPK + i
  const int h = blockIdx.y;         // half: 0 or 1
  const int t = threadIdx.x;
  const int p = sidx[bi];
  const float4* src =
      (const float4*)(prompt + (size_t)p * L * D) + h * 1024;
  float4* dst = (float4*)(out + (size_t)bi * (L * D)) + h * 1024;
#pragma unroll
  for (int c = 0; c < 4; ++c)       // 1024 float4 / 256 threads
    dst[c * 256 + t] = src[c * 256 + t];
}

// ---------------------------------------------------------------------------
extern "C" void kernel_launch(void* const* d_in, const int* in_sizes, int n_in,
                              void* d_out, int out_size, void* d_ws,
                              size_t ws_size, hipStream_t stream) {
  const float* x_embed    = (const float*)d_in[0];  // [B,S,D]
  const float* prompt     = (const float*)d_in[1];  // [P,L,D]
  const float* prompt_key = (const float*)d_in[2];  // [P,D]
  const float* gumbel_u   = (const float*)d_in[3];  // [TOPK,B,P]
  float* out = (float*)d_out;                       // [B,TOPK*L,D]

  // ws layout (~5.3 MB): simp | qm | alpha | beta | sidx
  float* simp  = (float*)d_ws;                     // KSPLIT*B*P = 1048576 f
  float* qm    = simp + (size_t)KSPLIT * B * P;    // B*D        =  262144 f
  float* alpha = qm + (size_t)B * D;               // B
  float* beta  = alpha + B;                        // P
  int*   sidx  = (int*)(beta + P);                 // B*TOPK ints

  query_norm_kernel<<<B + PKB, 1024, 0, stream>>>(x_embed, prompt_key, qm,
                                                  alpha, beta);
  sim_kernel<<<dim3(B / 64, P / 64, KSPLIT), 256, 0, stream>>>(qm, prompt_key,
                                                               simp);
  select_kernel<<<B, 512, 0, stream>>>(simp, alpha, beta, gumbel_u, sidx);
  gather_kernel<<<dim3(B * TOPK, 2), 256, 0, stream>>>(sidx, prompt, out);
}